// Round 1
// 411.763 us; speedup vs baseline: 1.0541x; 1.0541x over previous
//
#include <hip/hip_runtime.h>
#include <cstdint>
#include <cstddef>

// PositionalEncoderGrid: Instant-NGP multiresolution hash grid.
// B=524288 points, L=16 levels, T=2^19 entries/level, F=2 floats.
//
// R8: - Phase A split into TWO temporal passes, ONE level per XCD per pass
//       (pass 1: levels 8-15, pass 2: levels 0-7). The XOR hash scatters
//       indices over the full 4 MiB table even at coarse n, so per-level
//       working sets are {0.3..3.6 MiB} for l0-5 and ~4 MiB for l6-15 --
//       no pairing of two levels fits one XCD's 4 MiB L2 (R7's pairing put
//       up to 8 MiB on 4 MiB -> 297 MB FETCH, 4.6x table over-fetch).
//       One level per XCD per pass fits exactly.
//     - Table loads are now CACHED (R7 marked them nt -- actively evicting
//       the reused data); input loads + ws stores stay nt so streaming
//       traffic does not evict the table from L2.
//     - Phase B: unchanged LDS-tiled transpose (dense per-level reads,
//       256x128B coalesced nt float4 writes).

#define NUM_LEVELS 16
#define TBL_MASK ((1u << 19) - 1u)
#define PRIME_Y 2654435761u
#define PRIME_Z 805459861u
#define BATCH 524288

typedef float nfloat4 __attribute__((ext_vector_type(4)));

__constant__ float c_ns[NUM_LEVELS] = {
    16.f, 20.f, 25.f, 32.f, 40.f, 50.f, 64.f, 80.f,
    101.f, 128.f, 161.f, 203.f, 256.f, 322.f, 406.f, 512.f
};

struct Corner8 {
    uint32_t i[8];
    float wx0, wy0, wz0;
};

__device__ __forceinline__ float2 d2f2(double d) {
    union { double d; float2 f; } u;
    u.d = d;
    return u.f;
}

__device__ __forceinline__ double f22d(float2 f) {
    union { double d; float2 f; } u;
    u.f = f;
    return u.d;
}

// Corner indices + fractional weights for one (already-normalized) point at
// resolution n.
__device__ __forceinline__ Corner8 corner_setup_xyz(
    float xs, float ys, float zs, float n)
{
    const float tx = xs * n, ty = ys * n, tz = zs * n;
    const float fpx = floorf(tx), fpy = floorf(ty), fpz = floorf(tz);

    Corner8 c;
    c.wx0 = tx - fpx;
    c.wy0 = ty - fpy;
    c.wz0 = tz - fpz;

    const uint32_t px = (uint32_t)fpx;
    const uint32_t py = (uint32_t)fpy;
    const uint32_t pz = (uint32_t)fpz;

    const uint32_t hx0 = px;
    const uint32_t hx1 = px + 1u;
    const uint32_t hy0 = py * PRIME_Y;
    const uint32_t hy1 = hy0 + PRIME_Y;
    const uint32_t hz0 = pz * PRIME_Z;
    const uint32_t hz1 = hz0 + PRIME_Z;

    c.i[0] = (hx0 ^ hy0 ^ hz0) & TBL_MASK;
    c.i[1] = (hx0 ^ hy0 ^ hz1) & TBL_MASK;
    c.i[2] = (hx0 ^ hy1 ^ hz0) & TBL_MASK;
    c.i[3] = (hx0 ^ hy1 ^ hz1) & TBL_MASK;
    c.i[4] = (hx1 ^ hy0 ^ hz0) & TBL_MASK;
    c.i[5] = (hx1 ^ hy0 ^ hz1) & TBL_MASK;
    c.i[6] = (hx1 ^ hy1 ^ hz0) & TBL_MASK;
    c.i[7] = (hx1 ^ hy1 ^ hz1) & TBL_MASK;
    return c;
}

__device__ __forceinline__ float2 blend(const Corner8& c, const float2 f[8])
{
    const float wx1 = c.wx0, wx0 = 1.0f - c.wx0;
    const float wy1 = c.wy0, wy0 = 1.0f - c.wy0;
    const float wz1 = c.wz0, wz0 = 1.0f - c.wz0;

    float a0 = 0.0f, a1 = 0.0f, w;
    w = wx0 * wy0 * wz0; a0 = fmaf(f[0].x, w, a0); a1 = fmaf(f[0].y, w, a1);
    w = wx0 * wy0 * wz1; a0 = fmaf(f[1].x, w, a0); a1 = fmaf(f[1].y, w, a1);
    w = wx0 * wy1 * wz0; a0 = fmaf(f[2].x, w, a0); a1 = fmaf(f[2].y, w, a1);
    w = wx0 * wy1 * wz1; a0 = fmaf(f[3].x, w, a0); a1 = fmaf(f[3].y, w, a1);
    w = wx1 * wy0 * wz0; a0 = fmaf(f[4].x, w, a0); a1 = fmaf(f[4].y, w, a1);
    w = wx1 * wy0 * wz1; a0 = fmaf(f[5].x, w, a0); a1 = fmaf(f[5].y, w, a1);
    w = wx1 * wy1 * wz0; a0 = fmaf(f[6].x, w, a0); a1 = fmaf(f[6].y, w, a1);
    w = wx1 * wy1 * wz1; a0 = fmaf(f[7].x, w, a0); a1 = fmaf(f[7].y, w, a1);
    return make_float2(a0, a1);
}

// Phase A: each block handles 256 points for ONE level; level = base + XCD
// slot, so each XCD's L2 holds exactly one level's table for the whole pass.
__global__ __launch_bounds__(256) void enc_level_kernel(
    const float* __restrict__ in,
    const float* __restrict__ table,
    double* __restrict__ ws,           // [L, B] float2 as double
    int base_level)
{
    const int slot = blockIdx.x & 7;           // -> XCD slot
    const int chunk = blockIdx.x >> 3;         // 2048 chunks of 256 points
    const int l = base_level + slot;
    const int p = chunk * 256 + threadIdx.x;

    // Streaming input: nt so it doesn't evict the L2-resident table.
    const float vx = __builtin_nontemporal_load(&in[p * 3 + 0]);
    const float vy = __builtin_nontemporal_load(&in[p * 3 + 1]);
    const float vz = __builtin_nontemporal_load(&in[p * 3 + 2]);
    const float xs = (vx + 3.0f) / 6.0f;
    const float ys = (vy + 3.0f) / 6.0f;
    const float zs = (vz + 3.0f) / 6.0f;

    const Corner8 c = corner_setup_xyz(xs, ys, zs, c_ns[l]);

    const double* __restrict__ tb = ((const double*)table) + ((size_t)l << 19);

    // All 8 gathers in flight before first use; CACHED loads -- the whole
    // point of the per-XCD level pinning is that these hit L2.
    float2 f[8];
#pragma unroll
    for (int k = 0; k < 8; ++k) f[k] = d2f2(tb[c.i[k]]);

    __builtin_nontemporal_store(f22d(blend(c, f)), &ws[(size_t)l * BATCH + p]);
}

// Phase B: LDS-tiled transpose [L,B] -> [B,L]. Block stages 256 points x 16
// levels (dense 2KB reads per level), writes 256x128B coalesced.
__global__ __launch_bounds__(256) void transpose_kernel(
    const double* __restrict__ ws,     // [L, B] float2 as double
    nfloat4* __restrict__ out)         // [B*8]
{
    __shared__ double lds[256][NUM_LEVELS + 1];   // +1 pad: 34B-row stride

    const int tid = threadIdx.x;
    const int p0 = blockIdx.x * 256;

#pragma unroll
    for (int l = 0; l < NUM_LEVELS; ++l) {
        lds[tid][l] = __builtin_nontemporal_load(&ws[(size_t)l * BATCH + p0 + tid]);
    }
    __syncthreads();

    // 2048 float4s per block; lane-contiguous stores.
#pragma unroll
    for (int it = 0; it < 8; ++it) {
        const int e = it * 256 + tid;
        const int p = e >> 3;          // point within tile
        const int j = e & 7;           // float4 index within point
        const float2 a = d2f2(lds[p][2 * j]);
        const float2 b = d2f2(lds[p][2 * j + 1]);
        nfloat4 r;
        r.x = a.x; r.y = a.y; r.z = b.x; r.w = b.y;
        __builtin_nontemporal_store(r, &out[(size_t)blockIdx.x * 2048 + e]);
    }
}

// Fallback: direct scatter store (no workspace needed).
__global__ __launch_bounds__(256) void enc_scatter_kernel(
    const float* __restrict__ in,
    const float* __restrict__ table,
    float2* __restrict__ out)          // [B, 16] float2
{
    const int v = blockIdx.x & 15;
    const int chunk = blockIdx.x >> 4;
    const int l = (v < 8) ? (15 - v) : (v - 8);
    const int p = chunk * 256 + threadIdx.x;

    const float vx = in[p * 3 + 0];
    const float vy = in[p * 3 + 1];
    const float vz = in[p * 3 + 2];
    const Corner8 c = corner_setup_xyz((vx + 3.0f) / 6.0f, (vy + 3.0f) / 6.0f,
                                       (vz + 3.0f) / 6.0f, c_ns[l]);
    const double* __restrict__ tb = ((const double*)table) + ((size_t)l << 19);
    float2 f[8];
#pragma unroll
    for (int k = 0; k < 8; ++k) f[k] = d2f2(tb[c.i[k]]);
    out[(size_t)p * NUM_LEVELS + l] = blend(c, f);
}

extern "C" void kernel_launch(void* const* d_in, const int* in_sizes, int n_in,
                              void* d_out, int out_size, void* d_ws, size_t ws_size,
                              hipStream_t stream) {
    const float* inputs = (const float*)d_in[0];   // [B,3] fp32
    const float* table  = (const float*)d_in[1];   // [16, 2^19, 2] fp32

    const size_t ws_needed = (size_t)NUM_LEVELS * BATCH * sizeof(float2); // 64 MiB

    if (ws_size >= ws_needed) {
        double* ws = (double*)d_ws;
        // Phase A pass 1: levels 8-15, one level per XCD (4 MiB table == L2).
        enc_level_kernel<<<16384, 256, 0, stream>>>(inputs, table, ws, 8);
        // Phase A pass 2: levels 0-7 (footprints 0.3-4 MiB, all fit L2).
        enc_level_kernel<<<16384, 256, 0, stream>>>(inputs, table, ws, 0);
        // Phase B: 524288/256 = 2048 blocks.
        transpose_kernel<<<2048, 256, 0, stream>>>(ws, (nfloat4*)d_out);
    } else {
        enc_scatter_kernel<<<32768, 256, 0, stream>>>(inputs, table, (float2*)d_out);
    }
}